// Round 15
// baseline (1757.477 us; speedup 1.0000x reference)
//
#include <hip/hip_runtime.h>
#include <math.h>

#define HH 128
#define WW 128
#define CIN 512
#define NPIX 16384
#define NPRE 6000
#define NPOST 300
#define NMW 94          // u64 words per mask row: ceil(6000/64)

// workspace offsets in FLOATS (XS/WB regions are bf16 ushort pairs; MASK u64;
// LOG doubles — all 8B-aligned)
#define WS_XS1    0ull          // 8388608 ushort = 4194304 floats
#define WS_XS2    4194304ull
#define WS_XS3    8388608ull
#define WS_WB1    12582912ull   // 2359296 ushort = 1179648 floats
#define WS_WB2    13762560ull
#define WS_WB3    14942208ull
#define WS_LIST   16121856ull   // 16384 ints
#define WS_NACT   16138240ull   // 1 int
#define WS_MASK   16138248ull   // 564000 u64 = 1128000 floats
#define WS_LOG    17266248ull   // 196608 doubles = 393216 floats
#define WS_ROI    17659464ull   // 16384*4
#define WS_SC32   17725000ull   // 16384
#define WS_CAND   17741384ull   // 6000*4
#define WS_TOPS   17765384ull   // 6000

// d_out offsets (floats), concatenated tuple in return order
#define O_LOCS   0
#define O_ROIS   65536
#define O_RIDX   66736
#define O_ANCHOR 67036
#define O_CLS    132572
#define O_COS    247260
#define O_RSC    263644
#define O_OLD    263944

typedef short bf16x8 __attribute__((ext_vector_type(8)));
typedef float f32x4 __attribute__((ext_vector_type(4)));

__device__ __forceinline__ float exp32(float x) { return (float)exp((double)x); }
__device__ __forceinline__ float sqrt32(float x) { return (float)sqrt((double)x); }

__device__ __forceinline__ unsigned short bf16t(float v) {
  return (unsigned short)(__float_as_uint(v) >> 16);   // truncate to bf16
}
__device__ __forceinline__ float bf2f(unsigned short u) {
  return __uint_as_float((unsigned)u << 16);
}
// exact 3-way split: v == bf2f(s1)+bf2f(s2)+bf2f(s3) for normal f32
__device__ __forceinline__ void split3(float v, unsigned short& s1,
                                       unsigned short& s2, unsigned short& s3) {
  s1 = bf16t(v);
  float r = v - bf2f(s1);
  s2 = bf16t(r);
  float r2 = r - bf2f(s2);
  s3 = bf16t(r2);
}

// ---- fused prep:
//  blocks 0..2047    : x transpose+split -> xs1/2/3[pix][c] (bf16, LDS tile)
//  blocks 2048..2494 : zero logits
//  block  2495       : compacted active-pixel list
//  blocks 2496..4543 : weight split -> wb1/2/3[(j*512+oc)*512+c] (bf16)
__global__ __launch_bounds__(256) void prep_kernel(
    const float* __restrict__ x, const float* __restrict__ w,
    unsigned short* __restrict__ xs1, unsigned short* __restrict__ xs2,
    unsigned short* __restrict__ xs3, unsigned short* __restrict__ wb1,
    unsigned short* __restrict__ wb2, unsigned short* __restrict__ wb3,
    double* __restrict__ logits, const int* __restrict__ mask,
    int* __restrict__ list, int* __restrict__ nact) {
  int b = blockIdx.x;
  int tid = threadIdx.x;
  if (b < 2048) {
    __shared__ float t[64][65];
    int p0 = (b & 255) * 64;
    int c0 = (b >> 8) * 64;
    int lo = tid & 63;
    int q = tid >> 6;
#pragma unroll
    for (int ii = 0; ii < 16; ++ii) {
      int cc = q + ii * 4;
      t[cc][lo] = x[(size_t)(c0 + cc) * NPIX + p0 + lo];
    }
    __syncthreads();
#pragma unroll
    for (int ii = 0; ii < 16; ++ii) {
      int pp = q + ii * 4;
      float v = t[lo][pp];
      unsigned short s1, s2, s3;
      split3(v, s1, s2, s3);
      size_t addr = (size_t)(p0 + pp) * 512 + c0 + lo;
      xs1[addr] = s1; xs2[addr] = s2; xs3[addr] = s3;
    }
  } else if (b < 2495) {
    int i = (b - 2048) * 256 + tid;
    const int stride = 447 * 256;
    for (; i < NPIX * 12; i += stride) logits[i] = 0.0;
  } else if (b == 2495) {
    __shared__ int sc[256];
    int base = tid << 6;
    int cnt = 0;
    for (int i = 0; i < 64; ++i) cnt += (mask[base + i] != 0);
    sc[tid] = cnt;
    __syncthreads();
    for (int off = 1; off < 256; off <<= 1) {
      int v = 0;
      if (tid >= off) v = sc[tid - off];
      __syncthreads();
      sc[tid] += v;
      __syncthreads();
    }
    int pos = sc[tid] - cnt;
    for (int i = 0; i < 64; ++i)
      if (mask[base + i] != 0) list[pos++] = base + i;
    if (tid == 255) nact[0] = sc[255];
  } else {
    // wb split: linear id == destination index (j*512+oc)*512 + c
    int id = (b - 2496) * 256 + tid;
    const int stride = 2048 * 256;
    for (; id < 9 * 512 * 512; id += stride) {
      int c = id & 511;
      int oc = (id >> 9) & 511;
      int j = id >> 18;
      float v = w[(size_t)oc * 4608 + c * 9 + j];
      unsigned short s1, s2, s3;
      split3(v, s1, s2, s3);
      wb1[id] = s1; wb2[id] = s2; wb3[id] = s3;
    }
  }
}

// ------- implicit-GEMM conv via EXACT 3x bf16 split + mfma 16x16x32 ----------
// R9 decomposition (wave = 16 pixels x 64 outch, runtime-balanced XCD swizzle).
// x*y = x1y1 + (x1y2+x2y1) + (x1y3+x2y2+x3y1); dropped terms ~2^-26 rel —
// better than the f32 precision of the reference itself. Fragments per the
// HW-verified gfx950 16x16x32 bf16 layouts: A[m=lane&15][k=(lane>>4)*8+e],
// B[k=(lane>>4)*8+e][n=lane&15], C/D col=lane&15 row=(lane>>4)*4+reg.
// K-dim per chunk = 32 consecutive channels at one tap; 16 chunks x 9 taps.
__global__ __launch_bounds__(256, 2) void conv_bf16_kernel(
    const unsigned short* __restrict__ xs1, const unsigned short* __restrict__ xs2,
    const unsigned short* __restrict__ xs3, const unsigned short* __restrict__ wb1,
    const unsigned short* __restrict__ wb2, const unsigned short* __restrict__ wb3,
    const float* __restrict__ bias, const float* __restrict__ loc_w,
    const float* __restrict__ cls_w, const float* __restrict__ cos_w,
    const int* __restrict__ list, const int* __restrict__ nact,
    double* __restrict__ logits) {
  int tid = threadIdx.x;
  int lane = tid & 63;
  int wv = tid >> 6;                  // wave 0..3
  int n = nact[0];
  int ntg = (n + 63) >> 6;
  int total = ntg << 3;               // work items: w = tg*8 + g
  int lin = blockIdx.x;
  int xcd = lin & 7;
  int slot = lin >> 3;
  int wpx = (total + 7) >> 3;
  int w = xcd * wpx + slot;
  if (slot >= wpx || w >= total) return;   // block-uniform exit
  int tg = w >> 3;
  int m0 = (w & 7) << 6;
  int tile = tg * 4 + wv;
  if (tile * 16 >= n) return;         // wave-uniform exit; no barriers
  int col = lane & 15;
  int kk = lane >> 4;

  int slotp = tile * 16 + col;        // A-row pixel for this lane
  int p = (slotp < n) ? list[slotp] : -1;
  bool pv = (p >= 0);
  int py = p >> 7, px = p & 127;

  int offj[9];
  bool valj[9];
#pragma unroll
  for (int j = 0; j < 9; ++j) {
    int dy = j / 3 - 1, dx = j % 3 - 1;
    int yy = py + dy, xx = px + dx;
    bool v = pv && (yy >= 0) && (yy < HH) && (xx >= 0) && (xx < WW);
    valj[j] = v;
    offj[j] = v ? (yy * WW + xx) : 0;
  }

  f32x4 acc[4];
#pragma unroll
  for (int nf = 0; nf < 4; ++nf) acc[nf] = (f32x4){0.f, 0.f, 0.f, 0.f};

  const bf16x8 zzv = (bf16x8){0, 0, 0, 0, 0, 0, 0, 0};
  int ka = kk * 8;
  int bcol[4];
#pragma unroll
  for (int nf = 0; nf < 4; ++nf) bcol[nf] = (m0 + nf * 16 + col) * 512;

  for (int c0 = 0; c0 < CIN; c0 += 32) {
    int kc = c0 + ka;
#pragma unroll
    for (int j = 0; j < 9; ++j) {
      size_t axi = (size_t)offj[j] * 512 + kc;
      bf16x8 a1 = *(const bf16x8*)(xs1 + axi);
      bf16x8 a2 = *(const bf16x8*)(xs2 + axi);
      bf16x8 a3 = *(const bf16x8*)(xs3 + axi);
      a1 = valj[j] ? a1 : zzv;
      a2 = valj[j] ? a2 : zzv;
      a3 = valj[j] ? a3 : zzv;
      int wjb = j * (512 * 512) + kc;
      bf16x8 B1[4], B2[4], B3[4];
#pragma unroll
      for (int nf = 0; nf < 4; ++nf) {
        B1[nf] = *(const bf16x8*)(wb1 + wjb + bcol[nf]);
        B2[nf] = *(const bf16x8*)(wb2 + wjb + bcol[nf]);
        B3[nf] = *(const bf16x8*)(wb3 + wjb + bcol[nf]);
      }
#pragma unroll
      for (int nf = 0; nf < 4; ++nf)
        acc[nf] = __builtin_amdgcn_mfma_f32_16x16x32_bf16(a1, B1[nf], acc[nf], 0, 0, 0);
#pragma unroll
      for (int nf = 0; nf < 4; ++nf)
        acc[nf] = __builtin_amdgcn_mfma_f32_16x16x32_bf16(a1, B2[nf], acc[nf], 0, 0, 0);
#pragma unroll
      for (int nf = 0; nf < 4; ++nf)
        acc[nf] = __builtin_amdgcn_mfma_f32_16x16x32_bf16(a2, B1[nf], acc[nf], 0, 0, 0);
#pragma unroll
      for (int nf = 0; nf < 4; ++nf)
        acc[nf] = __builtin_amdgcn_mfma_f32_16x16x32_bf16(a1, B3[nf], acc[nf], 0, 0, 0);
#pragma unroll
      for (int nf = 0; nf < 4; ++nf)
        acc[nf] = __builtin_amdgcn_mfma_f32_16x16x32_bf16(a2, B2[nf], acc[nf], 0, 0, 0);
#pragma unroll
      for (int nf = 0; nf < 4; ++nf)
        acc[nf] = __builtin_amdgcn_mfma_f32_16x16x32_bf16(a3, B1[nf], acc[nf], 0, 0, 0);
    }
  }

  // epilogue: lane (col,kk), reg jj = D[pixel row kk*4+jj][outch m0+nf*16+col]
#pragma unroll
  for (int jj = 0; jj < 4; ++jj) {
    float hvj[4];
#pragma unroll
    for (int nf = 0; nf < 4; ++nf) {
      float bb = bias[m0 + nf * 16 + col];
      hvj[nf] = fmaxf(__fadd_rn(acc[nf][jj], bb), 0.f);
    }
    int s2 = tile * 16 + kk * 4 + jj;
    bool wr = (col == 0) && (s2 < n);
    int pix = wr ? list[s2] : 0;
#pragma unroll
    for (int r = 0; r < 12; ++r) {
      double t = 0.0;
#pragma unroll
      for (int nf = 0; nf < 4; ++nf) {
        int oc = m0 + nf * 16 + col;
        float wh = (r < 4) ? loc_w[r * 512 + oc]
                           : (r < 11) ? cls_w[(r - 4) * 512 + oc] : cos_w[oc];
        t += (double)hvj[nf] * (double)wh;
      }
#pragma unroll
      for (int o = 8; o; o >>= 1) t += __shfl_xor(t, o, 16);
      if (wr) atomicAdd(&logits[(size_t)pix * 12 + r], t);
    }
  }
}

// ---- fused finalize+roi (R13, verified) -------------------------------------
__global__ __launch_bounds__(256) void finroi_kernel(
    const double* __restrict__ logits, const float* __restrict__ loc_b,
    const float* __restrict__ cls_b, const float* __restrict__ cos_b,
    const int* __restrict__ img_h, const int* __restrict__ img_w,
    float* __restrict__ out, float* __restrict__ roi,
    float* __restrict__ scores32) {
  int p = blockIdx.x * 256 + threadIdx.x;
  const double* lg = &logits[(size_t)p * 12];
  float l4[4];
#pragma unroll
  for (int o = 0; o < 4; ++o) {
    l4[o] = (float)(lg[o] + (double)loc_b[o]);
    out[O_LOCS + p * 4 + o] = l4[o];
  }
  double cl[7];
#pragma unroll
  for (int i = 0; i < 7; ++i) {
    cl[i] = lg[4 + i] + (double)cls_b[i];
    out[O_CLS + p * 7 + i] = (float)cl[i];
  }
  double z = lg[11] + (double)cos_b[0];
  double sig = 1.0 / (1.0 + exp(-z));
  out[O_COS + p] = (float)sig;
  double pm = cl[0];
  int ai = 0;
#pragma unroll
  for (int i = 1; i < 7; ++i)
    if (cl[i] > pm) { pm = cl[i]; ai = i; }
  double mx = cl[0];
#pragma unroll
  for (int i = 1; i < 7; ++i) mx = fmax(mx, cl[i]);
  double S = 0.0;
#pragma unroll
  for (int i = 0; i < 7; ++i) S += exp(cl[i] - mx);
  double p0 = exp(cl[0] - mx) / S;
  float fg = (float)(1.0 - p0);
  const float BS[7] = {16.f, 9.f, 14.f, 21.f, 33.f, 54.f, 93.f};
  float ascale_p = BS[ai];
  double cl0[7];
#pragma unroll
  for (int i = 0; i < 7; ++i) cl0[i] = logits[4 + i] + (double)cls_b[i];
  double pm0 = cl0[0];
  int ai0 = 0;
#pragma unroll
  for (int i = 1; i < 7; ++i)
    if (cl0[i] > pm0) { pm0 = cl0[i]; ai0 = i; }
  float ascale0 = BS[ai0];
  double z0 = logits[11] + (double)cos_b[0];
  float a0 = (float)(1.0 / (1.0 + exp(-z0)));
  if (a0 == 0.0f) a0 = __fadd_rn(a0, 1e-5f);
  float t1 = __fmul_rn(a0, a0);
  float t2 = __fdiv_rn(1.0f, t1);
  float t3 = __fsub_rn(t2, 1.0f);
  float anchor_h = __fmul_rn(ascale0, sqrt32(t3));
  float anchor_w = ascale_p;
  float ay = __fadd_rn((float)(p >> 7) * 8.0f, 4.0f);
  float ax = __fadd_rn((float)(p & 127) * 8.0f, 4.0f);
  float A0 = __fsub_rn(ay, __fmul_rn(0.5f, anchor_h));
  float A1 = __fsub_rn(ax, __fmul_rn(0.5f, anchor_w));
  float A2 = __fadd_rn(ay, __fmul_rn(0.5f, anchor_h));
  float A3 = __fadd_rn(ax, __fmul_rn(0.5f, anchor_w));
  *(float4*)&out[O_ANCHOR + p * 4] = make_float4(A0, A1, A2, A3);
  float hA = __fsub_rn(A2, A0), wA = __fsub_rn(A3, A1);
  float cy = __fadd_rn(A0, __fmul_rn(0.5f, hA));
  float cx = __fadd_rn(A1, __fmul_rn(0.5f, wA));
  float ncy = __fadd_rn(__fmul_rn(l4[0], hA), cy);
  float ncx = __fadd_rn(__fmul_rn(l4[1], wA), cx);
  float nh = __fmul_rn(exp32(l4[2]), hA);
  float nw = __fmul_rn(exp32(l4[3]), wA);
  float b0 = __fsub_rn(ncy, __fmul_rn(0.5f, nh));
  float b1 = __fsub_rn(ncx, __fmul_rn(0.5f, nw));
  float b2 = __fadd_rn(ncy, __fmul_rn(0.5f, nh));
  float b3 = __fadd_rn(ncx, __fmul_rn(0.5f, nw));
  float IH = (float)img_h[0], IW = (float)img_w[0];
  b0 = fminf(fmaxf(b0, 0.f), IH);
  b1 = fminf(fmaxf(b1, 0.f), IW);
  b2 = fminf(fmaxf(b2, 0.f), IH);
  b3 = fminf(fmaxf(b3, 0.f), IW);
  *(float4*)&roi[p * 4] = make_float4(b0, b1, b2, b3);
  float hs = __fsub_rn(b2, b0), wd = __fsub_rn(b3, b1);
  bool valid = (ai > 0) && (hs >= 16.f) && (wd >= 16.f);
  scores32[p] = valid ? fg : -INFINITY;
}

// ----- exact rank-selection (same key order as the old stable sort) ----------
__global__ __launch_bounds__(256) void rank_kernel(
    const float* __restrict__ scores32, const float* __restrict__ roi,
    float* __restrict__ out, float* __restrict__ cand, float* __restrict__ tops) {
  __shared__ unsigned long long kt[2048];
  int tid = threadIdx.x;
  int i = blockIdx.x * 256 + tid;
  unsigned u = __float_as_uint(scores32[i]);
  u = (u & 0x80000000u) ? ~u : (u | 0x80000000u);
  unsigned long long mykey = ((unsigned long long)u << 32) | (unsigned)(16383 - i);
  int rank = 0;
  for (int t0 = 0; t0 < 16384; t0 += 2048) {
    __syncthreads();
#pragma unroll
    for (int s = 0; s < 8; ++s) {
      int j = t0 + s * 256 + tid;
      unsigned uj = __float_as_uint(scores32[j]);
      uj = (uj & 0x80000000u) ? ~uj : (uj | 0x80000000u);
      kt[s * 256 + tid] = ((unsigned long long)uj << 32) | (unsigned)(16383 - j);
    }
    __syncthreads();
    for (int t = 0; t < 2048; ++t)
      rank += (kt[t] > mykey) ? 1 : 0;
  }
  if (rank < NPRE) {
    float s = scores32[i];
    float4 b = make_float4(0.f, 0.f, 0.f, 0.f);
    if (isfinite(s)) b = *(const float4*)&roi[i * 4];
    ((float4*)(out + O_OLD))[rank] = b;
    ((float4*)cand)[rank] = b;
    tops[rank] = s;
  }
}

// ----- NMS stage 1: whole-GPU pairwise suppression mask ----------------------
__global__ __launch_bounds__(64) void nms_mask_kernel(
    const float* __restrict__ cand, unsigned long long* __restrict__ mask) {
  __shared__ float cy0[64], cx0[64], cy1[64], cx1[64], car[64];
  int bw = blockIdx.x;
  int bj = blockIdx.y;
  int t = threadIdx.x;
  int c = bw * 64 + t;
  if (c < NPRE) {
    float4 b = ((const float4*)cand)[c];
    cy0[t] = b.x; cx0[t] = b.y; cy1[t] = b.z; cx1[t] = b.w;
    car[t] = __fmul_rn(__fsub_rn(b.z, b.x), __fsub_rn(b.w, b.y));
  } else {
    cy0[t] = 0.f; cx0[t] = 0.f; cy1[t] = 0.f; cx1[t] = 0.f; car[t] = 0.f;
  }
  __syncthreads();
  int r = bj * 64 + t;
  if (r >= NPRE) return;
  float4 rb = ((const float4*)cand)[r];
  float rar = __fmul_rn(__fsub_rn(rb.z, rb.x), __fsub_rn(rb.w, rb.y));
  unsigned long long bits = 0;
#pragma unroll 4
  for (int b = 0; b < 64; ++b) {
    int j = bw * 64 + b;
    float yy0 = fmaxf(cy0[b], rb.x), xx0 = fmaxf(cx0[b], rb.y);
    float yy1 = fminf(cy1[b], rb.z), xx1 = fminf(cx1[b], rb.w);
    float inter = __fmul_rn(fmaxf(__fsub_rn(yy1, yy0), 0.f),
                            fmaxf(__fsub_rn(xx1, xx0), 0.f));
    float den = __fadd_rn(__fsub_rn(__fadd_rn(car[b], rar), inter), 1e-9f);
    float iou = __fdiv_rn(inter, den);
    if (j > r && j < NPRE && iou > 0.7f)
      bits |= 1ull << b;
  }
  mask[(size_t)r * NMW + bw] = bits;
}

// ----- NMS stage 2: tiny serial reduce over the bitmask ----------------------
__global__ __launch_bounds__(128) void nms_reduce_kernel(
    const float* __restrict__ cand, const float* __restrict__ tops,
    const unsigned long long* __restrict__ mask, float* __restrict__ out) {
  __shared__ unsigned long long remv[NMW];
  __shared__ int red2[2];
  int tid = threadIdx.x;
  int lane = tid & 63, wid = tid >> 6;
  if (tid < NMW) remv[tid] = 0ull;
  __syncthreads();
  int kdone = NPOST;
  for (int k = 0; k < NPOST; ++k) {
    int cnd = 0x7FFFFFFF;
    if (tid < NMW) {
      unsigned long long avail = ~remv[tid];
      if (tid == NMW - 1) avail &= (1ull << (NPRE - (NMW - 1) * 64)) - 1;
      if (avail) cnd = (tid << 6) + (int)__builtin_ctzll(avail);
    }
#pragma unroll
    for (int off = 32; off; off >>= 1) {
      int o = __shfl_xor(cnd, off, 64);
      cnd = min(cnd, o);
    }
    if (lane == 0) red2[wid] = cnd;
    __syncthreads();
    int pick = min(red2[0], red2[1]);
    bool valid = (pick != 0x7FFFFFFF) && (tops[pick] != -INFINITY);
    if (!valid) { kdone = k; break; }
    if (tid == 0) {
      float4 b = ((const float4*)cand)[pick];
      out[O_ROIS + k * 4 + 0] = b.x;
      out[O_ROIS + k * 4 + 1] = b.y;
      out[O_ROIS + k * 4 + 2] = b.z;
      out[O_ROIS + k * 4 + 3] = b.w;
      out[O_RSC + k] = tops[pick];
    }
    if (tid < NMW) {
      unsigned long long m = mask[(size_t)pick * NMW + tid];
      if (tid == (pick >> 6)) m |= 1ull << (pick & 63);
      remv[tid] |= m;
    }
    __syncthreads();
  }
  for (int t = kdone + tid; t < NPOST; t += 128) {
    out[O_ROIS + t * 4 + 0] = 0.f;
    out[O_ROIS + t * 4 + 1] = 0.f;
    out[O_ROIS + t * 4 + 2] = 0.f;
    out[O_ROIS + t * 4 + 3] = 0.f;
    out[O_RSC + t] = 0.f;
  }
  for (int t = tid; t < NPOST; t += 128) out[O_RIDX + t] = 0.f;
}

extern "C" void kernel_launch(void* const* d_in, const int* in_sizes, int n_in,
                              void* d_out, int out_size, void* d_ws, size_t ws_size,
                              hipStream_t stream) {
  (void)in_sizes; (void)n_in; (void)out_size; (void)ws_size;
  const float* x      = (const float*)d_in[0];
  const int*   skel   = (const int*)d_in[1];
  const float* conv_w = (const float*)d_in[2];
  const float* conv_b = (const float*)d_in[3];
  const float* loc_w  = (const float*)d_in[4];
  const float* loc_b  = (const float*)d_in[5];
  const float* cls_w  = (const float*)d_in[6];
  const float* cls_b  = (const float*)d_in[7];
  const float* cos_w  = (const float*)d_in[8];
  const float* cos_b  = (const float*)d_in[9];
  const int*   img_h  = (const int*)d_in[10];
  const int*   img_w  = (const int*)d_in[11];
  float* out = (float*)d_out;
  float* ws  = (float*)d_ws;

  unsigned short* xs1 = (unsigned short*)(ws + WS_XS1);
  unsigned short* xs2 = (unsigned short*)(ws + WS_XS2);
  unsigned short* xs3 = (unsigned short*)(ws + WS_XS3);
  unsigned short* wb1 = (unsigned short*)(ws + WS_WB1);
  unsigned short* wb2 = (unsigned short*)(ws + WS_WB2);
  unsigned short* wb3 = (unsigned short*)(ws + WS_WB3);
  int*    list     = (int*)(ws + WS_LIST);
  int*    nact     = (int*)(ws + WS_NACT);
  unsigned long long* nmsmask = (unsigned long long*)(ws + WS_MASK);
  double* logits   = (double*)(ws + WS_LOG);
  float*  roi      = ws + WS_ROI;
  float*  scores32 = ws + WS_SC32;
  float*  cand     = ws + WS_CAND;
  float*  tops     = ws + WS_TOPS;

  hipLaunchKernelGGL(prep_kernel, dim3(4544), dim3(256), 0, stream, x, conv_w,
                     xs1, xs2, xs3, wb1, wb2, wb3, logits, skel, list, nact);
  hipLaunchKernelGGL(conv_bf16_kernel, dim3(2048), dim3(256), 0, stream, xs1, xs2,
                     xs3, wb1, wb2, wb3, conv_b, loc_w, cls_w, cos_w, list, nact,
                     logits);
  hipLaunchKernelGGL(finroi_kernel, dim3(64), dim3(256), 0, stream, logits, loc_b,
                     cls_b, cos_b, img_h, img_w, out, roi, scores32);
  hipLaunchKernelGGL(rank_kernel, dim3(64), dim3(256), 0, stream, scores32, roi, out,
                     cand, tops);
  hipLaunchKernelGGL(nms_mask_kernel, dim3(NMW, NMW), dim3(64), 0, stream, cand,
                     nmsmask);
  hipLaunchKernelGGL(nms_reduce_kernel, dim3(1), dim3(128), 0, stream, cand, tops,
                     nmsmask, out);
}

// Round 16
// 1069.944 us; speedup vs baseline: 1.6426x; 1.6426x over previous
//
#include <hip/hip_runtime.h>
#include <math.h>

#define HH 128
#define WW 128
#define CIN 512
#define NPIX 16384
#define NPRE 6000
#define NPOST 300
#define NMW 94          // u64 words per mask row: ceil(6000/64)

// workspace offsets in FLOATS (XS/WB regions are bf16 ushort pairs; MASK u64;
// LOG doubles — all 8B-aligned)
#define WS_XS1    0ull          // 8388608 ushort = 4194304 floats
#define WS_XS2    4194304ull
#define WS_XS3    8388608ull
#define WS_WB1    12582912ull   // 2359296 ushort = 1179648 floats
#define WS_WB2    13762560ull
#define WS_WB3    14942208ull
#define WS_LIST   16121856ull   // 16384 ints
#define WS_NACT   16138240ull   // 1 int
#define WS_MASK   16138248ull   // 564000 u64 = 1128000 floats
#define WS_LOG    17266248ull   // 196608 doubles = 393216 floats
#define WS_ROI    17659464ull   // 16384*4
#define WS_SC32   17725000ull   // 16384
#define WS_CAND   17741384ull   // 6000*4
#define WS_TOPS   17765384ull   // 6000

// d_out offsets (floats), concatenated tuple in return order
#define O_LOCS   0
#define O_ROIS   65536
#define O_RIDX   66736
#define O_ANCHOR 67036
#define O_CLS    132572
#define O_COS    247260
#define O_RSC    263644
#define O_OLD    263944

typedef short bf16x8 __attribute__((ext_vector_type(8)));
typedef float f32x4 __attribute__((ext_vector_type(4)));

__device__ __forceinline__ float exp32(float x) { return (float)exp((double)x); }
__device__ __forceinline__ float sqrt32(float x) { return (float)sqrt((double)x); }

__device__ __forceinline__ unsigned short bf16t(float v) {
  return (unsigned short)(__float_as_uint(v) >> 16);   // truncate to bf16
}
__device__ __forceinline__ float bf2f(unsigned short u) {
  return __uint_as_float((unsigned)u << 16);
}
// exact 3-way split: v == bf2f(s1)+bf2f(s2)+bf2f(s3) for normal f32
__device__ __forceinline__ void split3(float v, unsigned short& s1,
                                       unsigned short& s2, unsigned short& s3) {
  s1 = bf16t(v);
  float r = v - bf2f(s1);
  s2 = bf16t(r);
  float r2 = r - bf2f(s2);
  s3 = bf16t(r2);
}

// ---- fused prep:
//  blocks 0..2047    : x transpose+split -> xs1/2/3[pix][c] (bf16, LDS tile)
//  blocks 2048..2494 : zero logits
//  block  2495       : compacted active-pixel list
//  blocks 2496..4543 : weight split -> wb[((j*64+c/8)*512+oc)*8 + c%8]
//                      (FRAGMENT-CONTIGUOUS: lane col -> oc adjacent -> 16B
//                       blocks adjacent -> coalesced B loads; R15's [j][oc][c]
//                       layout was a 64-line gather per load = 7.7% MfmaUtil)
__global__ __launch_bounds__(256) void prep_kernel(
    const float* __restrict__ x, const float* __restrict__ w,
    unsigned short* __restrict__ xs1, unsigned short* __restrict__ xs2,
    unsigned short* __restrict__ xs3, unsigned short* __restrict__ wb1,
    unsigned short* __restrict__ wb2, unsigned short* __restrict__ wb3,
    double* __restrict__ logits, const int* __restrict__ mask,
    int* __restrict__ list, int* __restrict__ nact) {
  int b = blockIdx.x;
  int tid = threadIdx.x;
  if (b < 2048) {
    __shared__ float t[64][65];
    int p0 = (b & 255) * 64;
    int c0 = (b >> 8) * 64;
    int lo = tid & 63;
    int q = tid >> 6;
#pragma unroll
    for (int ii = 0; ii < 16; ++ii) {
      int cc = q + ii * 4;
      t[cc][lo] = x[(size_t)(c0 + cc) * NPIX + p0 + lo];
    }
    __syncthreads();
#pragma unroll
    for (int ii = 0; ii < 16; ++ii) {
      int pp = q + ii * 4;
      float v = t[lo][pp];
      unsigned short s1, s2, s3;
      split3(v, s1, s2, s3);
      size_t addr = (size_t)(p0 + pp) * 512 + c0 + lo;
      xs1[addr] = s1; xs2[addr] = s2; xs3[addr] = s3;
    }
  } else if (b < 2495) {
    int i = (b - 2048) * 256 + tid;
    const int stride = 447 * 256;
    for (; i < NPIX * 12; i += stride) logits[i] = 0.0;
  } else if (b == 2495) {
    __shared__ int sc[256];
    int base = tid << 6;
    int cnt = 0;
    for (int i = 0; i < 64; ++i) cnt += (mask[base + i] != 0);
    sc[tid] = cnt;
    __syncthreads();
    for (int off = 1; off < 256; off <<= 1) {
      int v = 0;
      if (tid >= off) v = sc[tid - off];
      __syncthreads();
      sc[tid] += v;
      __syncthreads();
    }
    int pos = sc[tid] - cnt;
    for (int i = 0; i < 64; ++i)
      if (mask[base + i] != 0) list[pos++] = base + i;
    if (tid == 255) nact[0] = sc[255];
  } else {
    // wb split: linear id == destination index ((j*64+cb)*512+oc)*8 + ce
    int id = (b - 2496) * 256 + tid;
    const int stride = 2048 * 256;
    for (; id < 9 * 512 * 512; id += stride) {
      int ce = id & 7;
      int oc = (id >> 3) & 511;
      int rest = id >> 12;           // j*64 + cb
      int j = rest >> 6;
      int cb = rest & 63;
      int c = cb * 8 + ce;
      float v = w[(size_t)oc * 4608 + c * 9 + j];
      unsigned short s1, s2, s3;
      split3(v, s1, s2, s3);
      wb1[id] = s1; wb2[id] = s2; wb3[id] = s3;
    }
  }
}

// ------- implicit-GEMM conv via EXACT 3x bf16 split + mfma 16x16x32 ----------
// R9 decomposition (wave = 16 pixels x 64 outch, runtime-balanced XCD swizzle).
// x*y = x1y1 + (x1y2+x2y1) + (x1y3+x2y2+x3y1); dropped terms ~2^-26 rel.
// Fragments per HW-verified gfx950 16x16x32 bf16 layouts. B loads now
// coalesced via the fragment-contiguous wb layout.
__global__ __launch_bounds__(256, 2) void conv_bf16_kernel(
    const unsigned short* __restrict__ xs1, const unsigned short* __restrict__ xs2,
    const unsigned short* __restrict__ xs3, const unsigned short* __restrict__ wb1,
    const unsigned short* __restrict__ wb2, const unsigned short* __restrict__ wb3,
    const float* __restrict__ bias, const float* __restrict__ loc_w,
    const float* __restrict__ cls_w, const float* __restrict__ cos_w,
    const int* __restrict__ list, const int* __restrict__ nact,
    double* __restrict__ logits) {
  int tid = threadIdx.x;
  int lane = tid & 63;
  int wv = tid >> 6;                  // wave 0..3
  int n = nact[0];
  int ntg = (n + 63) >> 6;
  int total = ntg << 3;               // work items: w = tg*8 + g
  int lin = blockIdx.x;
  int xcd = lin & 7;
  int slot = lin >> 3;
  int wpx = (total + 7) >> 3;
  int w = xcd * wpx + slot;
  if (slot >= wpx || w >= total) return;   // block-uniform exit
  int tg = w >> 3;
  int m0 = (w & 7) << 6;
  int tile = tg * 4 + wv;
  if (tile * 16 >= n) return;         // wave-uniform exit; no barriers
  int col = lane & 15;
  int kk = lane >> 4;

  int slotp = tile * 16 + col;        // A-row pixel for this lane
  int p = (slotp < n) ? list[slotp] : -1;
  bool pv = (p >= 0);
  int py = p >> 7, px = p & 127;

  int offj[9];
  bool valj[9];
#pragma unroll
  for (int j = 0; j < 9; ++j) {
    int dy = j / 3 - 1, dx = j % 3 - 1;
    int yy = py + dy, xx = px + dx;
    bool v = pv && (yy >= 0) && (yy < HH) && (xx >= 0) && (xx < WW);
    valj[j] = v;
    offj[j] = v ? (yy * WW + xx) : 0;
  }

  f32x4 acc[4];
#pragma unroll
  for (int nf = 0; nf < 4; ++nf) acc[nf] = (f32x4){0.f, 0.f, 0.f, 0.f};

  const bf16x8 zzv = (bf16x8){0, 0, 0, 0, 0, 0, 0, 0};
  int ka = kk * 8;
  int bcol[4];
#pragma unroll
  for (int nf = 0; nf < 4; ++nf) bcol[nf] = (m0 + nf * 16 + col) * 8;

  for (int c0 = 0; c0 < CIN; c0 += 32) {
    int kc = c0 + ka;
    int cb = kc >> 3;                  // c-block for this lane's kk-group
#pragma unroll
    for (int j = 0; j < 9; ++j) {
      size_t axi = (size_t)offj[j] * 512 + kc;
      bf16x8 a1 = *(const bf16x8*)(xs1 + axi);
      bf16x8 a2 = *(const bf16x8*)(xs2 + axi);
      bf16x8 a3 = *(const bf16x8*)(xs3 + axi);
      a1 = valj[j] ? a1 : zzv;
      a2 = valj[j] ? a2 : zzv;
      a3 = valj[j] ? a3 : zzv;
      int wjb = (j * 64 + cb) * 4096;  // (j*64+cb)*512*8
      bf16x8 B1[4], B2[4], B3[4];
#pragma unroll
      for (int nf = 0; nf < 4; ++nf) {
        B1[nf] = *(const bf16x8*)(wb1 + wjb + bcol[nf]);
        B2[nf] = *(const bf16x8*)(wb2 + wjb + bcol[nf]);
        B3[nf] = *(const bf16x8*)(wb3 + wjb + bcol[nf]);
      }
#pragma unroll
      for (int nf = 0; nf < 4; ++nf)
        acc[nf] = __builtin_amdgcn_mfma_f32_16x16x32_bf16(a1, B1[nf], acc[nf], 0, 0, 0);
#pragma unroll
      for (int nf = 0; nf < 4; ++nf)
        acc[nf] = __builtin_amdgcn_mfma_f32_16x16x32_bf16(a1, B2[nf], acc[nf], 0, 0, 0);
#pragma unroll
      for (int nf = 0; nf < 4; ++nf)
        acc[nf] = __builtin_amdgcn_mfma_f32_16x16x32_bf16(a2, B1[nf], acc[nf], 0, 0, 0);
#pragma unroll
      for (int nf = 0; nf < 4; ++nf)
        acc[nf] = __builtin_amdgcn_mfma_f32_16x16x32_bf16(a1, B3[nf], acc[nf], 0, 0, 0);
#pragma unroll
      for (int nf = 0; nf < 4; ++nf)
        acc[nf] = __builtin_amdgcn_mfma_f32_16x16x32_bf16(a2, B2[nf], acc[nf], 0, 0, 0);
#pragma unroll
      for (int nf = 0; nf < 4; ++nf)
        acc[nf] = __builtin_amdgcn_mfma_f32_16x16x32_bf16(a3, B1[nf], acc[nf], 0, 0, 0);
    }
  }

  // epilogue: lane (col,kk), reg jj = D[pixel row kk*4+jj][outch m0+nf*16+col]
#pragma unroll
  for (int jj = 0; jj < 4; ++jj) {
    float hvj[4];
#pragma unroll
    for (int nf = 0; nf < 4; ++nf) {
      float bb = bias[m0 + nf * 16 + col];
      hvj[nf] = fmaxf(__fadd_rn(acc[nf][jj], bb), 0.f);
    }
    int s2 = tile * 16 + kk * 4 + jj;
    bool wr = (col == 0) && (s2 < n);
    int pix = wr ? list[s2] : 0;
#pragma unroll
    for (int r = 0; r < 12; ++r) {
      double t = 0.0;
#pragma unroll
      for (int nf = 0; nf < 4; ++nf) {
        int oc = m0 + nf * 16 + col;
        float wh = (r < 4) ? loc_w[r * 512 + oc]
                           : (r < 11) ? cls_w[(r - 4) * 512 + oc] : cos_w[oc];
        t += (double)hvj[nf] * (double)wh;
      }
#pragma unroll
      for (int o = 8; o; o >>= 1) t += __shfl_xor(t, o, 16);
      if (wr) atomicAdd(&logits[(size_t)pix * 12 + r], t);
    }
  }
}

// ---- fused finalize+roi (R13, verified) -------------------------------------
__global__ __launch_bounds__(256) void finroi_kernel(
    const double* __restrict__ logits, const float* __restrict__ loc_b,
    const float* __restrict__ cls_b, const float* __restrict__ cos_b,
    const int* __restrict__ img_h, const int* __restrict__ img_w,
    float* __restrict__ out, float* __restrict__ roi,
    float* __restrict__ scores32) {
  int p = blockIdx.x * 256 + threadIdx.x;
  const double* lg = &logits[(size_t)p * 12];
  float l4[4];
#pragma unroll
  for (int o = 0; o < 4; ++o) {
    l4[o] = (float)(lg[o] + (double)loc_b[o]);
    out[O_LOCS + p * 4 + o] = l4[o];
  }
  double cl[7];
#pragma unroll
  for (int i = 0; i < 7; ++i) {
    cl[i] = lg[4 + i] + (double)cls_b[i];
    out[O_CLS + p * 7 + i] = (float)cl[i];
  }
  double z = lg[11] + (double)cos_b[0];
  double sig = 1.0 / (1.0 + exp(-z));
  out[O_COS + p] = (float)sig;
  double pm = cl[0];
  int ai = 0;
#pragma unroll
  for (int i = 1; i < 7; ++i)
    if (cl[i] > pm) { pm = cl[i]; ai = i; }
  double mx = cl[0];
#pragma unroll
  for (int i = 1; i < 7; ++i) mx = fmax(mx, cl[i]);
  double S = 0.0;
#pragma unroll
  for (int i = 0; i < 7; ++i) S += exp(cl[i] - mx);
  double p0 = exp(cl[0] - mx) / S;
  float fg = (float)(1.0 - p0);
  const float BS[7] = {16.f, 9.f, 14.f, 21.f, 33.f, 54.f, 93.f};
  float ascale_p = BS[ai];
  double cl0[7];
#pragma unroll
  for (int i = 0; i < 7; ++i) cl0[i] = logits[4 + i] + (double)cls_b[i];
  double pm0 = cl0[0];
  int ai0 = 0;
#pragma unroll
  for (int i = 1; i < 7; ++i)
    if (cl0[i] > pm0) { pm0 = cl0[i]; ai0 = i; }
  float ascale0 = BS[ai0];
  double z0 = logits[11] + (double)cos_b[0];
  float a0 = (float)(1.0 / (1.0 + exp(-z0)));
  if (a0 == 0.0f) a0 = __fadd_rn(a0, 1e-5f);
  float t1 = __fmul_rn(a0, a0);
  float t2 = __fdiv_rn(1.0f, t1);
  float t3 = __fsub_rn(t2, 1.0f);
  float anchor_h = __fmul_rn(ascale0, sqrt32(t3));
  float anchor_w = ascale_p;
  float ay = __fadd_rn((float)(p >> 7) * 8.0f, 4.0f);
  float ax = __fadd_rn((float)(p & 127) * 8.0f, 4.0f);
  float A0 = __fsub_rn(ay, __fmul_rn(0.5f, anchor_h));
  float A1 = __fsub_rn(ax, __fmul_rn(0.5f, anchor_w));
  float A2 = __fadd_rn(ay, __fmul_rn(0.5f, anchor_h));
  float A3 = __fadd_rn(ax, __fmul_rn(0.5f, anchor_w));
  *(float4*)&out[O_ANCHOR + p * 4] = make_float4(A0, A1, A2, A3);
  float hA = __fsub_rn(A2, A0), wA = __fsub_rn(A3, A1);
  float cy = __fadd_rn(A0, __fmul_rn(0.5f, hA));
  float cx = __fadd_rn(A1, __fmul_rn(0.5f, wA));
  float ncy = __fadd_rn(__fmul_rn(l4[0], hA), cy);
  float ncx = __fadd_rn(__fmul_rn(l4[1], wA), cx);
  float nh = __fmul_rn(exp32(l4[2]), hA);
  float nw = __fmul_rn(exp32(l4[3]), wA);
  float b0 = __fsub_rn(ncy, __fmul_rn(0.5f, nh));
  float b1 = __fsub_rn(ncx, __fmul_rn(0.5f, nw));
  float b2 = __fadd_rn(ncy, __fmul_rn(0.5f, nh));
  float b3 = __fadd_rn(ncx, __fmul_rn(0.5f, nw));
  float IH = (float)img_h[0], IW = (float)img_w[0];
  b0 = fminf(fmaxf(b0, 0.f), IH);
  b1 = fminf(fmaxf(b1, 0.f), IW);
  b2 = fminf(fmaxf(b2, 0.f), IH);
  b3 = fminf(fmaxf(b3, 0.f), IW);
  *(float4*)&roi[p * 4] = make_float4(b0, b1, b2, b3);
  float hs = __fsub_rn(b2, b0), wd = __fsub_rn(b3, b1);
  bool valid = (ai > 0) && (hs >= 16.f) && (wd >= 16.f);
  scores32[p] = valid ? fg : -INFINITY;
}

// ----- exact rank-selection (same key order as the old stable sort) ----------
__global__ __launch_bounds__(256) void rank_kernel(
    const float* __restrict__ scores32, const float* __restrict__ roi,
    float* __restrict__ out, float* __restrict__ cand, float* __restrict__ tops) {
  __shared__ unsigned long long kt[2048];
  int tid = threadIdx.x;
  int i = blockIdx.x * 256 + tid;
  unsigned u = __float_as_uint(scores32[i]);
  u = (u & 0x80000000u) ? ~u : (u | 0x80000000u);
  unsigned long long mykey = ((unsigned long long)u << 32) | (unsigned)(16383 - i);
  int rank = 0;
  for (int t0 = 0; t0 < 16384; t0 += 2048) {
    __syncthreads();
#pragma unroll
    for (int s = 0; s < 8; ++s) {
      int j = t0 + s * 256 + tid;
      unsigned uj = __float_as_uint(scores32[j]);
      uj = (uj & 0x80000000u) ? ~uj : (uj | 0x80000000u);
      kt[s * 256 + tid] = ((unsigned long long)uj << 32) | (unsigned)(16383 - j);
    }
    __syncthreads();
    for (int t = 0; t < 2048; ++t)
      rank += (kt[t] > mykey) ? 1 : 0;
  }
  if (rank < NPRE) {
    float s = scores32[i];
    float4 b = make_float4(0.f, 0.f, 0.f, 0.f);
    if (isfinite(s)) b = *(const float4*)&roi[i * 4];
    ((float4*)(out + O_OLD))[rank] = b;
    ((float4*)cand)[rank] = b;
    tops[rank] = s;
  }
}

// ----- NMS stage 1: whole-GPU pairwise suppression mask ----------------------
__global__ __launch_bounds__(64) void nms_mask_kernel(
    const float* __restrict__ cand, unsigned long long* __restrict__ mask) {
  __shared__ float cy0[64], cx0[64], cy1[64], cx1[64], car[64];
  int bw = blockIdx.x;
  int bj = blockIdx.y;
  int t = threadIdx.x;
  int c = bw * 64 + t;
  if (c < NPRE) {
    float4 b = ((const float4*)cand)[c];
    cy0[t] = b.x; cx0[t] = b.y; cy1[t] = b.z; cx1[t] = b.w;
    car[t] = __fmul_rn(__fsub_rn(b.z, b.x), __fsub_rn(b.w, b.y));
  } else {
    cy0[t] = 0.f; cx0[t] = 0.f; cy1[t] = 0.f; cx1[t] = 0.f; car[t] = 0.f;
  }
  __syncthreads();
  int r = bj * 64 + t;
  if (r >= NPRE) return;
  float4 rb = ((const float4*)cand)[r];
  float rar = __fmul_rn(__fsub_rn(rb.z, rb.x), __fsub_rn(rb.w, rb.y));
  unsigned long long bits = 0;
#pragma unroll 4
  for (int b = 0; b < 64; ++b) {
    int j = bw * 64 + b;
    float yy0 = fmaxf(cy0[b], rb.x), xx0 = fmaxf(cx0[b], rb.y);
    float yy1 = fminf(cy1[b], rb.z), xx1 = fminf(cx1[b], rb.w);
    float inter = __fmul_rn(fmaxf(__fsub_rn(yy1, yy0), 0.f),
                            fmaxf(__fsub_rn(xx1, xx0), 0.f));
    float den = __fadd_rn(__fsub_rn(__fadd_rn(car[b], rar), inter), 1e-9f);
    float iou = __fdiv_rn(inter, den);
    if (j > r && j < NPRE && iou > 0.7f)
      bits |= 1ull << b;
  }
  mask[(size_t)r * NMW + bw] = bits;
}

// ----- NMS stage 2: tiny serial reduce over the bitmask ----------------------
__global__ __launch_bounds__(128) void nms_reduce_kernel(
    const float* __restrict__ cand, const float* __restrict__ tops,
    const unsigned long long* __restrict__ mask, float* __restrict__ out) {
  __shared__ unsigned long long remv[NMW];
  __shared__ int red2[2];
  int tid = threadIdx.x;
  int lane = tid & 63, wid = tid >> 6;
  if (tid < NMW) remv[tid] = 0ull;
  __syncthreads();
  int kdone = NPOST;
  for (int k = 0; k < NPOST; ++k) {
    int cnd = 0x7FFFFFFF;
    if (tid < NMW) {
      unsigned long long avail = ~remv[tid];
      if (tid == NMW - 1) avail &= (1ull << (NPRE - (NMW - 1) * 64)) - 1;
      if (avail) cnd = (tid << 6) + (int)__builtin_ctzll(avail);
    }
#pragma unroll
    for (int off = 32; off; off >>= 1) {
      int o = __shfl_xor(cnd, off, 64);
      cnd = min(cnd, o);
    }
    if (lane == 0) red2[wid] = cnd;
    __syncthreads();
    int pick = min(red2[0], red2[1]);
    bool valid = (pick != 0x7FFFFFFF) && (tops[pick] != -INFINITY);
    if (!valid) { kdone = k; break; }
    if (tid == 0) {
      float4 b = ((const float4*)cand)[pick];
      out[O_ROIS + k * 4 + 0] = b.x;
      out[O_ROIS + k * 4 + 1] = b.y;
      out[O_ROIS + k * 4 + 2] = b.z;
      out[O_ROIS + k * 4 + 3] = b.w;
      out[O_RSC + k] = tops[pick];
    }
    if (tid < NMW) {
      unsigned long long m = mask[(size_t)pick * NMW + tid];
      if (tid == (pick >> 6)) m |= 1ull << (pick & 63);
      remv[tid] |= m;
    }
    __syncthreads();
  }
  for (int t = kdone + tid; t < NPOST; t += 128) {
    out[O_ROIS + t * 4 + 0] = 0.f;
    out[O_ROIS + t * 4 + 1] = 0.f;
    out[O_ROIS + t * 4 + 2] = 0.f;
    out[O_ROIS + t * 4 + 3] = 0.f;
    out[O_RSC + t] = 0.f;
  }
  for (int t = tid; t < NPOST; t += 128) out[O_RIDX + t] = 0.f;
}

extern "C" void kernel_launch(void* const* d_in, const int* in_sizes, int n_in,
                              void* d_out, int out_size, void* d_ws, size_t ws_size,
                              hipStream_t stream) {
  (void)in_sizes; (void)n_in; (void)out_size; (void)ws_size;
  const float* x      = (const float*)d_in[0];
  const int*   skel   = (const int*)d_in[1];
  const float* conv_w = (const float*)d_in[2];
  const float* conv_b = (const float*)d_in[3];
  const float* loc_w  = (const float*)d_in[4];
  const float* loc_b  = (const float*)d_in[5];
  const float* cls_w  = (const float*)d_in[6];
  const float* cls_b  = (const float*)d_in[7];
  const float* cos_w  = (const float*)d_in[8];
  const float* cos_b  = (const float*)d_in[9];
  const int*   img_h  = (const int*)d_in[10];
  const int*   img_w  = (const int*)d_in[11];
  float* out = (float*)d_out;
  float* ws  = (float*)d_ws;

  unsigned short* xs1 = (unsigned short*)(ws + WS_XS1);
  unsigned short* xs2 = (unsigned short*)(ws + WS_XS2);
  unsigned short* xs3 = (unsigned short*)(ws + WS_XS3);
  unsigned short* wb1 = (unsigned short*)(ws + WS_WB1);
  unsigned short* wb2 = (unsigned short*)(ws + WS_WB2);
  unsigned short* wb3 = (unsigned short*)(ws + WS_WB3);
  int*    list     = (int*)(ws + WS_LIST);
  int*    nact     = (int*)(ws + WS_NACT);
  unsigned long long* nmsmask = (unsigned long long*)(ws + WS_MASK);
  double* logits   = (double*)(ws + WS_LOG);
  float*  roi      = ws + WS_ROI;
  float*  scores32 = ws + WS_SC32;
  float*  cand     = ws + WS_CAND;
  float*  tops     = ws + WS_TOPS;

  hipLaunchKernelGGL(prep_kernel, dim3(4544), dim3(256), 0, stream, x, conv_w,
                     xs1, xs2, xs3, wb1, wb2, wb3, logits, skel, list, nact);
  hipLaunchKernelGGL(conv_bf16_kernel, dim3(2048), dim3(256), 0, stream, xs1, xs2,
                     xs3, wb1, wb2, wb3, conv_b, loc_w, cls_w, cos_w, list, nact,
                     logits);
  hipLaunchKernelGGL(finroi_kernel, dim3(64), dim3(256), 0, stream, logits, loc_b,
                     cls_b, cos_b, img_h, img_w, out, roi, scores32);
  hipLaunchKernelGGL(rank_kernel, dim3(64), dim3(256), 0, stream, scores32, roi, out,
                     cand, tops);
  hipLaunchKernelGGL(nms_mask_kernel, dim3(NMW, NMW), dim3(64), 0, stream, cand,
                     nmsmask);
  hipLaunchKernelGGL(nms_reduce_kernel, dim3(1), dim3(128), 0, stream, cand, tops,
                     nmsmask, out);
}